// Round 8
// baseline (286.896 us; speedup 1.0000x reference)
//
#include <hip/hip_runtime.h>
#include <hip/hip_bf16.h>
#include <stdint.h>

// Problem dims
#define NE 8
#define NT 1024
#define NH 2048
#define NI 1408
#define NI2 (2 * NI)  // 2816

typedef __attribute__((ext_vector_type(8))) short          bf16x8;
typedef __attribute__((ext_vector_type(8))) unsigned short u16x8;
typedef __attribute__((ext_vector_type(4))) unsigned short u16x4;
typedef __attribute__((ext_vector_type(4))) float          f32x4;

__device__ __forceinline__ unsigned short f2bf(float f) {
  union { float f; uint32_t u; } v; v.f = f;
  uint32_t u = v.u;
  return (unsigned short)((u + 0x7FFFu + ((u >> 16) & 1u)) >> 16);  // RNE
}

// async global->LDS, 16B per lane. LDS dest is wave-uniform base + lane*16.
__device__ __forceinline__ void gload_lds16(const void* g, void* l) {
  __builtin_amdgcn_global_load_lds(
      (const __attribute__((address_space(1))) uint32_t*)g,
      (__attribute__((address_space(3))) uint32_t*)l, 16, 0, 0);
}

#define WAITV0() asm volatile("s_waitcnt vmcnt(0)" ::: "memory")
#define BAR() do { __builtin_amdgcn_sched_barrier(0); \
                   __builtin_amdgcn_s_barrier();      \
                   __builtin_amdgcn_sched_barrier(0); } while (0)

// ---------------------------------------------------------------------------
// x: fp32 -> bf16 elementwise
// ---------------------------------------------------------------------------
__global__ __launch_bounds__(256) void cvt_bf16(const float* __restrict__ src,
                                                unsigned short* __restrict__ dst,
                                                int n8) {
  int i = blockIdx.x * blockDim.x + threadIdx.x;
  const int stride = gridDim.x * blockDim.x;
  for (; i < n8; i += stride) {
    const float4 f0 = ((const float4*)src)[i * 2];
    const float4 f1 = ((const float4*)src)[i * 2 + 1];
    u16x8 o;
    o[0] = f2bf(f0.x); o[1] = f2bf(f0.y); o[2] = f2bf(f0.z); o[3] = f2bf(f0.w);
    o[4] = f2bf(f1.x); o[5] = f2bf(f1.y); o[6] = f2bf(f1.z); o[7] = f2bf(f1.w);
    ((u16x8*)dst)[i] = o;
  }
}

// ---------------------------------------------------------------------------
// Transpose + cvt:  src [E][R][C] f32  ->  dst rows mapped from c, ld = R, bf16
// ilv=1: out row = ((c>>4)<<5) | (c&15) | radd   (16-col gate/up interleave)
// ---------------------------------------------------------------------------
__global__ __launch_bounds__(256) void transpose_cvt(
    const float* __restrict__ src, unsigned short* __restrict__ dst,
    int R, int C, long estride, int ilv, int radd) {
  __shared__ float tile[64][65];
  const int e  = blockIdx.z;
  const int c0 = blockIdx.x * 64;
  const int r0 = blockIdx.y * 64;
  const float* s = src + (size_t)e * R * C;
  unsigned short* d = dst + (size_t)e * estride;
  const int tid = threadIdx.x;
  const int tr  = tid >> 4;        // 0..15
  const int tc  = (tid & 15) * 4;  // 0..60
  #pragma unroll
  for (int it = 0; it < 4; ++it) {
    const int r = it * 16 + tr;
    float4 v = *(const float4*)(s + (size_t)(r0 + r) * C + c0 + tc);
    tile[r][tc + 0] = v.x; tile[r][tc + 1] = v.y;
    tile[r][tc + 2] = v.z; tile[r][tc + 3] = v.w;
  }
  __syncthreads();
  #pragma unroll
  for (int it = 0; it < 4; ++it) {
    const int oc = it * 16 + tr;
    const int c  = c0 + oc;
    const int ro = ilv ? ((((c >> 4) << 5) | (c & 15)) | radd) : c;
    u16x4 o;
    o[0] = f2bf(tile[tc + 0][oc]);
    o[1] = f2bf(tile[tc + 1][oc]);
    o[2] = f2bf(tile[tc + 2][oc]);
    o[3] = f2bf(tile[tc + 3][oc]);
    *(u16x4*)(d + (size_t)ro * R + r0 + tc) = o;
  }
}

// ---------------------------------------------------------------------------
// Async minimal-sync GEMM: C[e,m,n] = A[e,m,:] . B[e,n,:]  (bf16, K-contig)
// BM=BN=128, BK=64; 256 thr (4 waves 2Mx2N, wave tile 64x64).
// LDS 64 KB (2 bufs x 32 KB) -> 2 independent blocks/CU (async overlap).
// ONE barrier + ONE vmcnt(0) per K-tile:
//   [WAITV0 (stage(t) issued a full iter ago -> ~free)] [BAR]
//   [16 ds_read frags | STAGE(t+1 -> other buf) | 32 MFMA]  (compiler-sched)
// Stage-1-ahead into the buffer whose tenant (t-1) was consumed pre-BAR.
// T2 XOR-swizzle via pre-swizzled global source; T1 XCD chunks (1 expert/XCD).
// MODE 0: f32 out [E][1024][NBY*128]
// MODE 1: silu-pair bf16 out [E][1024][NBY*64] (B rows interleaved g16/u16)
// ---------------------------------------------------------------------------
template <int NBY, int KDIM, int MODE>
__global__ __launch_bounds__(256, 2) void gemm_async(
    const unsigned short* __restrict__ Ag,  // [E][1024][KDIM]
    const unsigned short* __restrict__ Bg,  // [E][NBY*128][KDIM]
    void* __restrict__ outp) {
  constexpr int KT    = KDIM / 64;   // 32 or 22 (even)
  constexpr int CHUNK = NBY * 8;     // blocks per XCD = one expert

  __shared__ __align__(16) unsigned short As[2][128 * 64];
  __shared__ __align__(16) unsigned short Bs[2][128 * 64];

  // XCD-chunked bijective swizzle (grid = 8 * CHUNK)
  const int flat = blockIdx.x;
  const int orig = (flat & 7) * CHUNK + (flat >> 3);
  const int e    = orig / CHUNK;
  const int r    = orig % CHUNK;
  const int by   = r >> 3;
  const int bx   = r & 7;

  const int bm  = bx * 128;
  const int bnn = by * 128;

  const int tid  = threadIdx.x;
  const int lane = tid & 63;
  const int w    = tid >> 6;        // 0..3
  const int wrm  = (w >> 1) * 64;   // wave M offset
  const int wcn  = (w & 1) * 64;    // wave N offset

  const unsigned short* Ae = Ag + (size_t)e * 1024 * KDIM;
  const unsigned short* Be = Bg + (size_t)e * (NBY * 128) * KDIM;

  // staging: per gload a wave covers 8 rows x 128B; lane l: row l>>3,
  // 16B chunk (l&7)^(l>>3)  (pre-swizzled source -> linear LDS dest equals
  // the XOR-swizzled layout the frag reads expect).
  const int l8 = lane >> 3;
  const int jx = (lane & 7) ^ l8;
  const unsigned short* aA = Ae + (size_t)(bm  + w * 32 + l8) * KDIM + jx * 8;
  const unsigned short* aB = Be + (size_t)(bnn + w * 32 + l8) * KDIM + jx * 8;

  f32x4 acc[4][4];
  #pragma unroll
  for (int i = 0; i < 4; ++i)
    #pragma unroll
    for (int j = 0; j < 4; ++j) acc[i][j] = f32x4{0.f, 0.f, 0.f, 0.f};

  // swizzled fragment read offset (bytes) within a 16-row frag; ^64 flips kk
  const int aoff = (lane & 15) * 128 + ((((lane >> 4) << 4)) ^ ((lane & 7) << 4));

  auto STAGE = [&](unsigned short* Ad, unsigned short* Bd, int t) {
    const int kb = t * 64;
    #pragma unroll
    for (int q = 0; q < 4; ++q)
      gload_lds16(aA + (size_t)q * 8 * KDIM + kb, Ad + (w * 32 + q * 8) * 64);
    #pragma unroll
    for (int q = 0; q < 4; ++q)
      gload_lds16(aB + (size_t)q * 8 * KDIM + kb, Bd + (w * 32 + q * 8) * 64);
  };

  auto ITER = [&](int t, const unsigned short* Ac, const unsigned short* Bc,
                  unsigned short* An, unsigned short* Bn) {
    WAITV0();   // drains stage(t): issued one full iteration ago
    BAR();      // all waves' stage(t) landed; t-1 reads all consumed
    const char* Ab = (const char*)Ac + wrm * 128;
    const char* Bb = (const char*)Bc + wcn * 128;
    bf16x8 a[4][2], b[4][2];
    #pragma unroll
    for (int mi = 0; mi < 4; ++mi) {
      a[mi][0] = *(const bf16x8*)(Ab + mi * 2048 + aoff);
      a[mi][1] = *(const bf16x8*)(Ab + mi * 2048 + (aoff ^ 64));
    }
    #pragma unroll
    for (int nj = 0; nj < 4; ++nj) {
      b[nj][0] = *(const bf16x8*)(Bb + nj * 2048 + aoff);
      b[nj][1] = *(const bf16x8*)(Bb + nj * 2048 + (aoff ^ 64));
    }
    if (t + 1 < KT) STAGE(An, Bn, t + 1);
    #pragma unroll
    for (int kk = 0; kk < 2; ++kk)
      #pragma unroll
      for (int mi = 0; mi < 4; ++mi)
        #pragma unroll
        for (int nj = 0; nj < 4; ++nj)
          acc[mi][nj] = __builtin_amdgcn_mfma_f32_16x16x32_bf16(
              a[mi][kk], b[nj][kk], acc[mi][nj], 0, 0, 0);
  };

  // prologue: stage tile 0 into buf0
  STAGE(As[0], Bs[0], 0);

  #pragma unroll 1
  for (int t = 0; t < KT; t += 2) {
    ITER(t,     As[0], Bs[0], As[1], Bs[1]);
    ITER(t + 1, As[1], Bs[1], As[0], Bs[0]);
  }

  const int crow = (lane >> 4) * 4;
  const int ccol = lane & 15;
  if constexpr (MODE == 0) {
    float* oe = (float*)outp + (size_t)e * 1024 * (NBY * 128);
    #pragma unroll
    for (int mi = 0; mi < 4; ++mi)
      #pragma unroll
      for (int nj = 0; nj < 4; ++nj)
        #pragma unroll
        for (int j = 0; j < 4; ++j) {
          const int row = bm + wrm + mi * 16 + crow + j;
          const int col = bnn + wcn + nj * 16 + ccol;
          oe[(size_t)row * (NBY * 128) + col] = acc[mi][nj][j];
        }
  } else {
    // silu-pair: frag nj=2p is gate cols, nj=2p+1 the matching up cols
    unsigned short* he = (unsigned short*)outp + (size_t)e * 1024 * (NBY * 64);
    const int hcb = by * 64 + (wcn >> 1);
    #pragma unroll
    for (int mi = 0; mi < 4; ++mi)
      #pragma unroll
      for (int p = 0; p < 2; ++p)
        #pragma unroll
        for (int j = 0; j < 4; ++j) {
          const float g = acc[mi][2 * p][j];
          const float u = acc[mi][2 * p + 1][j];
          const float sv = g / (1.0f + __expf(-g)) * u;
          const int row = bm + wrm + mi * 16 + crow + j;
          const int col = hcb + p * 16 + ccol;
          he[(size_t)row * (NBY * 64) + col] = f2bf(sv);
        }
  }
}

// ---------------------------------------------------------------------------
extern "C" void kernel_launch(void* const* d_in, const int* in_sizes, int n_in,
                              void* d_out, int out_size, void* d_ws, size_t ws_size,
                              hipStream_t stream) {
  const float* x    = (const float*)d_in[0];  // [E][T][H]
  const float* gate = (const float*)d_in[1];  // [E][H][I]
  const float* up   = (const float*)d_in[2];  // [E][H][I]
  const float* down = (const float*)d_in[3];  // [E][I][H]
  float* out = (float*)d_out;                 // [E][T][H]

  // workspace (bf16): x_bf [E][T][H], wcat [E][2I][H] (g/u 16-col interleave),
  // dT [E][H][I], h [E][T][I].
  unsigned short* x_bf = (unsigned short*)d_ws;
  unsigned short* wcat = x_bf + (size_t)NE * NT * NH;
  unsigned short* dT   = wcat + (size_t)NE * NI2 * NH;
  unsigned short* hb   = dT   + (size_t)NE * NH * NI;

  cvt_bf16<<<2048, 256, 0, stream>>>(x, x_bf, NE * NT * NH / 8);

  transpose_cvt<<<dim3(NI / 64, NH / 64, NE), 256, 0, stream>>>(
      gate, wcat, NH, NI, (long)NI2 * NH, 1, 0);
  transpose_cvt<<<dim3(NI / 64, NH / 64, NE), 256, 0, stream>>>(
      up, wcat, NH, NI, (long)NI2 * NH, 1, 16);
  transpose_cvt<<<dim3(NH / 64, NI / 64, NE), 256, 0, stream>>>(
      down, dT, NI, NH, (long)NH * NI, 0, 0);

  // GEMM1: [1024 x 2816] = x_bf @ wcat^T, fused silu-pair -> h bf16.
  // 1408 blocks @ 2/CU.
  gemm_async<22, NH, 1><<<NE * 22 * 8, 256, 0, stream>>>(x_bf, wcat, hb);
  // GEMM2: [1024 x 2048] = h @ dT^T -> out f32. 1024 blocks = 2.0/CU exact.
  gemm_async<16, NI, 0><<<NE * 16 * 8, 256, 0, stream>>>(hb, dT, out);
}

// Round 9
// 285.429 us; speedup vs baseline: 1.0051x; 1.0051x over previous
//
#include <hip/hip_runtime.h>
#include <hip/hip_bf16.h>
#include <stdint.h>

// Problem dims
#define NE 8
#define NT 1024
#define NH 2048
#define NI 1408
#define NI2 (2 * NI)  // 2816

typedef __attribute__((ext_vector_type(8))) short          bf16x8;
typedef __attribute__((ext_vector_type(8))) unsigned short u16x8;
typedef __attribute__((ext_vector_type(4))) unsigned short u16x4;
typedef __attribute__((ext_vector_type(4))) float          f32x4;

__device__ __forceinline__ unsigned short f2bf(float f) {
  union { float f; uint32_t u; } v; v.f = f;
  uint32_t u = v.u;
  return (unsigned short)((u + 0x7FFFu + ((u >> 16) & 1u)) >> 16);  // RNE
}

// async global->LDS, 16B per lane. LDS dest is wave-uniform base + lane*16.
__device__ __forceinline__ void gload_lds16(const void* g, void* l) {
  __builtin_amdgcn_global_load_lds(
      (const __attribute__((address_space(1))) uint32_t*)g,
      (__attribute__((address_space(3))) uint32_t*)l, 16, 0, 0);
}

#define WAITV0() asm volatile("s_waitcnt vmcnt(0)" ::: "memory")
#define BAR() do { __builtin_amdgcn_sched_barrier(0); \
                   __builtin_amdgcn_s_barrier();      \
                   __builtin_amdgcn_sched_barrier(0); } while (0)

// ---------------------------------------------------------------------------
// x: fp32 -> bf16 elementwise
// ---------------------------------------------------------------------------
__global__ __launch_bounds__(256) void cvt_bf16(const float* __restrict__ src,
                                                unsigned short* __restrict__ dst,
                                                int n8) {
  int i = blockIdx.x * blockDim.x + threadIdx.x;
  const int stride = gridDim.x * blockDim.x;
  for (; i < n8; i += stride) {
    const float4 f0 = ((const float4*)src)[i * 2];
    const float4 f1 = ((const float4*)src)[i * 2 + 1];
    u16x8 o;
    o[0] = f2bf(f0.x); o[1] = f2bf(f0.y); o[2] = f2bf(f0.z); o[3] = f2bf(f0.w);
    o[4] = f2bf(f1.x); o[5] = f2bf(f1.y); o[6] = f2bf(f1.z); o[7] = f2bf(f1.w);
    ((u16x8*)dst)[i] = o;
  }
}

// ---------------------------------------------------------------------------
// Transpose + cvt:  src [E][R][C] f32  ->  dst rows mapped from c, ld = R, bf16
// ilv=1: out row = ((c>>4)<<5) | (c&15) | radd   (16-col gate/up interleave)
// ---------------------------------------------------------------------------
__global__ __launch_bounds__(256) void transpose_cvt(
    const float* __restrict__ src, unsigned short* __restrict__ dst,
    int R, int C, long estride, int ilv, int radd) {
  __shared__ float tile[64][65];
  const int e  = blockIdx.z;
  const int c0 = blockIdx.x * 64;
  const int r0 = blockIdx.y * 64;
  const float* s = src + (size_t)e * R * C;
  unsigned short* d = dst + (size_t)e * estride;
  const int tid = threadIdx.x;
  const int tr  = tid >> 4;        // 0..15
  const int tc  = (tid & 15) * 4;  // 0..60
  #pragma unroll
  for (int it = 0; it < 4; ++it) {
    const int r = it * 16 + tr;
    float4 v = *(const float4*)(s + (size_t)(r0 + r) * C + c0 + tc);
    tile[r][tc + 0] = v.x; tile[r][tc + 1] = v.y;
    tile[r][tc + 2] = v.z; tile[r][tc + 3] = v.w;
  }
  __syncthreads();
  #pragma unroll
  for (int it = 0; it < 4; ++it) {
    const int oc = it * 16 + tr;
    const int c  = c0 + oc;
    const int ro = ilv ? ((((c >> 4) << 5) | (c & 15)) | radd) : c;
    u16x4 o;
    o[0] = f2bf(tile[tc + 0][oc]);
    o[1] = f2bf(tile[tc + 1][oc]);
    o[2] = f2bf(tile[tc + 2][oc]);
    o[3] = f2bf(tile[tc + 3][oc]);
    *(u16x4*)(d + (size_t)ro * R + r0 + tc) = o;
  }
}

// ---------------------------------------------------------------------------
// Balanced async GEMM: C[e,m,n] = A[e,m,:] . B[e,n,:]  (bf16, K-contig)
// BM=256, BN=128, BK=32; 256 thr (4 waves 2Mx2N, wave tile 128x64 — balanced:
// 12 ds_read_b128 per 32 MFMA). LDS 48KB (2 bufs) -> 2 blocks/CU (8 waves,
// acc=128 AGPR). R8-proven single-sync K-loop: one vmcnt(0)+BAR per K-tile,
// draining loads issued a full iteration earlier; stage(t+1) -> other buf.
// BK=32 swizzle: chunk' = chunk ^ ((row>>1)&3)  (16B-granular, gload-compat,
// conflict-free in 8-lane LDS phases). T1 XCD chunks (1 expert per XCD).
// MODE 0: f32 out [E][1024][NBY*128]
// MODE 1: silu-pair bf16 out [E][1024][NBY*64] (B rows interleaved g16/u16)
// ---------------------------------------------------------------------------
template <int NBY, int KDIM, int MODE>
__global__ __launch_bounds__(256, 2) void gemm_bal(
    const unsigned short* __restrict__ Ag,  // [E][1024][KDIM]
    const unsigned short* __restrict__ Bg,  // [E][NBY*128][KDIM]
    void* __restrict__ outp) {
  constexpr int KT    = KDIM / 32;   // 64 or 44 (even)
  constexpr int CHUNK = 4 * NBY;     // blocks per XCD = one expert

  __shared__ __align__(16) unsigned short As[2][256 * 32];  // 16KB each
  __shared__ __align__(16) unsigned short Bs[2][128 * 32];  //  8KB each

  // XCD-chunked bijective swizzle (grid = 8 * CHUNK)
  const int flat = blockIdx.x;
  const int orig = (flat & 7) * CHUNK + (flat >> 3);
  const int e    = orig / CHUNK;
  const int r    = orig % CHUNK;
  const int bx   = r & 3;          // 4 M-blocks of 256
  const int by   = r >> 2;

  const int bm  = bx * 256;
  const int bnn = by * 128;

  const int tid  = threadIdx.x;
  const int lane = tid & 63;
  const int w    = tid >> 6;        // 0..3
  const int wrm  = (w >> 1) * 128;  // wave M offset
  const int wcn  = (w & 1) * 64;    // wave N offset

  const unsigned short* Ae = Ag + (size_t)e * 1024 * KDIM;
  const unsigned short* Be = Bg + (size_t)e * (NBY * 128) * KDIM;

  // staging: per gload a wave covers 16 rows x 64B; lane l: row l>>2,
  // 16B chunk (l&3)^((l>>3)&3)  (pre-swizzled source -> linear LDS dest
  // equals the (row>>1)&3-XOR layout the frag reads expect).
  const int l16 = lane >> 2;
  const int jx  = (lane & 3) ^ ((lane >> 3) & 3);
  const unsigned short* aA = Ae + (size_t)(bm  + w * 64 + l16) * KDIM + jx * 8;
  const unsigned short* aB = Be + (size_t)(bnn + w * 32 + l16) * KDIM + jx * 8;

  f32x4 acc[8][4];
  #pragma unroll
  for (int i = 0; i < 8; ++i)
    #pragma unroll
    for (int j = 0; j < 4; ++j) acc[i][j] = f32x4{0.f, 0.f, 0.f, 0.f};

  // swizzled fragment read offset (bytes) within a 16-row frag:
  // row=lane&15 (64B rows), chunk' = (lane>>4) ^ ((row>>1)&3)
  const int aoff = (lane & 15) * 64 +
                   (((lane >> 4) ^ (((lane & 15) >> 1) & 3)) * 16);

  auto STAGE = [&](unsigned short* Ad, unsigned short* Bd, int t) {
    const int kb = t * 32;
    #pragma unroll
    for (int q = 0; q < 4; ++q)
      gload_lds16(aA + (size_t)q * 16 * KDIM + kb, Ad + (w * 64 + q * 16) * 32);
    #pragma unroll
    for (int q = 0; q < 2; ++q)
      gload_lds16(aB + (size_t)q * 16 * KDIM + kb, Bd + (w * 32 + q * 16) * 32);
  };

  auto ITER = [&](int t, const unsigned short* Ac, const unsigned short* Bc,
                  unsigned short* An, unsigned short* Bn) {
    WAITV0();   // drains stage(t): issued one full iteration ago
    BAR();      // all waves' stage(t) landed; t-1 reads all consumed
    const char* Ab = (const char*)Ac + wrm * 64;
    const char* Bb = (const char*)Bc + wcn * 64;
    bf16x8 a[8], b[4];
    #pragma unroll
    for (int mi = 0; mi < 8; ++mi)
      a[mi] = *(const bf16x8*)(Ab + mi * 1024 + aoff);
    #pragma unroll
    for (int nj = 0; nj < 4; ++nj)
      b[nj] = *(const bf16x8*)(Bb + nj * 1024 + aoff);
    if (t + 1 < KT) STAGE(An, Bn, t + 1);
    #pragma unroll
    for (int mi = 0; mi < 8; ++mi)
      #pragma unroll
      for (int nj = 0; nj < 4; ++nj)
        acc[mi][nj] = __builtin_amdgcn_mfma_f32_16x16x32_bf16(
            a[mi], b[nj], acc[mi][nj], 0, 0, 0);
  };

  // prologue: stage tile 0 into buf0
  STAGE(As[0], Bs[0], 0);

  #pragma unroll 1
  for (int t = 0; t < KT; t += 2) {
    ITER(t,     As[0], Bs[0], As[1], Bs[1]);
    ITER(t + 1, As[1], Bs[1], As[0], Bs[0]);
  }

  const int crow = (lane >> 4) * 4;
  const int ccol = lane & 15;
  if constexpr (MODE == 0) {
    float* oe = (float*)outp + (size_t)e * 1024 * (NBY * 128);
    #pragma unroll
    for (int mi = 0; mi < 8; ++mi)
      #pragma unroll
      for (int nj = 0; nj < 4; ++nj)
        #pragma unroll
        for (int j = 0; j < 4; ++j) {
          const int row = bm + wrm + mi * 16 + crow + j;
          const int col = bnn + wcn + nj * 16 + ccol;
          oe[(size_t)row * (NBY * 128) + col] = acc[mi][nj][j];
        }
  } else {
    // silu-pair: frag nj=2p is gate cols, nj=2p+1 the matching up cols
    unsigned short* he = (unsigned short*)outp + (size_t)e * 1024 * (NBY * 64);
    const int hcb = by * 64 + (wcn >> 1);
    #pragma unroll
    for (int mi = 0; mi < 8; ++mi)
      #pragma unroll
      for (int p = 0; p < 2; ++p)
        #pragma unroll
        for (int j = 0; j < 4; ++j) {
          const float g = acc[mi][2 * p][j];
          const float u = acc[mi][2 * p + 1][j];
          const float sv = g / (1.0f + __expf(-g)) * u;
          const int row = bm + wrm + mi * 16 + crow + j;
          const int col = hcb + p * 16 + ccol;
          he[(size_t)row * (NBY * 64) + col] = f2bf(sv);
        }
  }
}

// ---------------------------------------------------------------------------
extern "C" void kernel_launch(void* const* d_in, const int* in_sizes, int n_in,
                              void* d_out, int out_size, void* d_ws, size_t ws_size,
                              hipStream_t stream) {
  const float* x    = (const float*)d_in[0];  // [E][T][H]
  const float* gate = (const float*)d_in[1];  // [E][H][I]
  const float* up   = (const float*)d_in[2];  // [E][H][I]
  const float* down = (const float*)d_in[3];  // [E][I][H]
  float* out = (float*)d_out;                 // [E][T][H]

  // workspace (bf16): x_bf [E][T][H], wcat [E][2I][H] (g/u 16-col interleave),
  // dT [E][H][I], h [E][T][I].
  unsigned short* x_bf = (unsigned short*)d_ws;
  unsigned short* wcat = x_bf + (size_t)NE * NT * NH;
  unsigned short* dT   = wcat + (size_t)NE * NI2 * NH;
  unsigned short* hb   = dT   + (size_t)NE * NH * NI;

  cvt_bf16<<<2048, 256, 0, stream>>>(x, x_bf, NE * NT * NH / 8);

  transpose_cvt<<<dim3(NI / 64, NH / 64, NE), 256, 0, stream>>>(
      gate, wcat, NH, NI, (long)NI2 * NH, 1, 0);
  transpose_cvt<<<dim3(NI / 64, NH / 64, NE), 256, 0, stream>>>(
      up, wcat, NH, NI, (long)NI2 * NH, 1, 16);
  transpose_cvt<<<dim3(NH / 64, NI / 64, NE), 256, 0, stream>>>(
      down, dT, NI, NH, (long)NH * NI, 0, 0);

  // GEMM1: [1024 x 2816] = x_bf @ wcat^T, fused silu-pair -> h bf16.
  // 704 blocks @ 2/CU.
  gemm_bal<22, NH, 1><<<NE * 4 * 22, 256, 0, stream>>>(x_bf, wcat, hb);
  // GEMM2: [1024 x 2048] = h @ dT^T -> out f32. 512 blocks = 2.0/CU exact.
  gemm_bal<16, NI, 0><<<NE * 4 * 16, 256, 0, stream>>>(hb, dT, out);
}